// Round 2
// baseline (310.051 us; speedup 1.0000x reference)
//
#include <hip/hip_runtime.h>
#include <math.h>

#define T_TOKENS 4096
#define HIDDEN   2048
#define N_EXPERTS 8

typedef float floatx4 __attribute__((ext_vector_type(4)));

// ---------------------------------------------------------------------------
// Kernel 1: fill router_indices [E*T, H] with value = (row % T), as float.
// Pure streaming write of 268 MB -> the roofline cost of this problem.
// float4 index i covers bytes [16i,16i+16); row = (4*i)/HIDDEN = i>>9;
// value = row & (T_TOKENS-1). Nontemporal stores keep L2 clean.
// ---------------------------------------------------------------------------
__global__ __launch_bounds__(256) void fill_indices_kernel(float* __restrict__ out1)
{
    const int n4 = (N_EXPERTS * T_TOKENS * HIDDEN) / 4;  // 16,777,216
    floatx4* o4 = (floatx4*)out1;
    int stride = gridDim.x * blockDim.x;
    for (int i = blockIdx.x * blockDim.x + threadIdx.x; i < n4; i += stride) {
        float v = (float)((i >> 9) & (T_TOKENS - 1));
        floatx4 x = {v, v, v, v};
        __builtin_nontemporal_store(x, &o4[i]);
    }
}

// ---------------------------------------------------------------------------
// Kernel 2: router logits + top-2 + sigmoid scatter.
// One wave per token. W (8x2048 f32 = 64 KB) staged in LDS once per block.
// Lane l handles h[t][k*256 + 4l .. +3] float4 chunks, k=0..7, accumulating
// 8 expert dots; shuffle-reduce across the 64-lane wave; lane 0 picks top-2,
// applies sigmoid, writes the dense [E,T] score column (zeros elsewhere)
// to both router_scores (out0) and router_probs (out2, same flat layout).
// ---------------------------------------------------------------------------
__global__ __launch_bounds__(256) void router_scores_kernel(
    const float* __restrict__ h, const float* __restrict__ w,
    float* __restrict__ out0, float* __restrict__ out2)
{
    __shared__ float wlds[N_EXPERTS * HIDDEN];  // 64 KB
    const float4* w4  = (const float4*)w;
    float4*       wl4 = (float4*)wlds;
    for (int i = threadIdx.x; i < (N_EXPERTS * HIDDEN) / 4; i += 256)
        wl4[i] = w4[i];
    __syncthreads();

    const int wave = threadIdx.x >> 6;
    const int lane = threadIdx.x & 63;
    const int t = blockIdx.x * 4 + wave;  // grid = 1024 blocks -> t in [0,4096)

    const float4* h4 = (const float4*)(h + (size_t)t * HIDDEN);
    float acc[N_EXPERTS];
    #pragma unroll
    for (int e = 0; e < N_EXPERTS; e++) acc[e] = 0.f;

    #pragma unroll
    for (int k = 0; k < 8; k++) {
        float4 hv = h4[k * 64 + lane];
        #pragma unroll
        for (int e = 0; e < N_EXPERTS; e++) {
            float4 wv = wl4[e * 512 + k * 64 + lane];
            acc[e] += hv.x * wv.x + hv.y * wv.y + hv.z * wv.z + hv.w * wv.w;
        }
    }

    // 64-lane shuffle reduction for each expert accumulator
    #pragma unroll
    for (int e = 0; e < N_EXPERTS; e++) {
        #pragma unroll
        for (int off = 32; off > 0; off >>= 1)
            acc[e] += __shfl_down(acc[e], off, 64);
    }

    if (lane == 0) {
        // top-2 of 8 (strict >, first-index-wins matches lax.top_k; order of
        // the two winners is irrelevant for the scattered output)
        int i1 = 0; float v1 = acc[0];
        #pragma unroll
        for (int e = 1; e < N_EXPERTS; e++)
            if (acc[e] > v1) { v1 = acc[e]; i1 = e; }
        int i2 = -1; float v2 = -INFINITY;
        #pragma unroll
        for (int e = 0; e < N_EXPERTS; e++)
            if (e != i1 && acc[e] > v2) { v2 = acc[e]; i2 = e; }

        float s1 = 1.f / (1.f + expf(-v1));
        float s2 = 1.f / (1.f + expf(-v2));

        #pragma unroll
        for (int e = 0; e < N_EXPERTS; e++) {
            float val = (e == i1) ? s1 : ((e == i2) ? s2 : 0.f);
            out0[e * T_TOKENS + t] = val;
            out2[e * T_TOKENS + t] = val;
        }
    }
}

extern "C" void kernel_launch(void* const* d_in, const int* in_sizes, int n_in,
                              void* d_out, int out_size, void* d_ws, size_t ws_size,
                              hipStream_t stream) {
    const float* h = (const float*)d_in[0];   // [4096, 2048] f32
    const float* w = (const float*)d_in[1];   // [8, 2048] f32
    // d_in[2] = top_k (always 2 for this problem)

    float* out  = (float*)d_out;
    float* out0 = out;                                   // router_scores [8,4096]
    float* out1 = out + N_EXPERTS * T_TOKENS;            // router_indices [32768,2048]
    float* out2 = out1 + (size_t)N_EXPERTS * T_TOKENS * HIDDEN;  // router_probs [32768,1]

    hipLaunchKernelGGL(fill_indices_kernel, dim3(8192), dim3(256), 0, stream, out1);
    hipLaunchKernelGGL(router_scores_kernel, dim3(1024), dim3(256), 0, stream,
                       h, w, out0, out2);
}

// Round 3
// 297.395 us; speedup vs baseline: 1.0426x; 1.0426x over previous
//
#include <hip/hip_runtime.h>
#include <math.h>

#define T_TOKENS 4096
#define HIDDEN   2048
#define N_EXPERTS 8

// ---------------------------------------------------------------------------
// Kernel 1: fill router_indices [E*T, H] with value = (row % T), as float.
// Pure streaming write of 268 MB -> the roofline cost of this problem.
// float4 index i covers bytes [16i,16i+16); row = (4*i)/HIDDEN = i>>9;
// value = row & (T_TOKENS-1).
// NOTE: plain stores, NOT __builtin_nontemporal_store — the nt flag on
// gfx950 bypassed L2 write-combining and ran at ~1 TB/s (R2: 310 us total
// vs rocclr memset of the same buffer at 6.3 TB/s).
// ---------------------------------------------------------------------------
__global__ __launch_bounds__(256) void fill_indices_kernel(float* __restrict__ out1)
{
    const int n4 = (N_EXPERTS * T_TOKENS * HIDDEN) / 4;  // 16,777,216
    float4* o4 = (float4*)out1;
    int stride = gridDim.x * blockDim.x;
    for (int i = blockIdx.x * blockDim.x + threadIdx.x; i < n4; i += stride) {
        float v = (float)((i >> 9) & (T_TOKENS - 1));
        o4[i] = make_float4(v, v, v, v);
    }
}

// ---------------------------------------------------------------------------
// Kernel 2: router logits + top-2 + sigmoid scatter.
// One wave per token. W (8x2048 f32 = 64 KB) staged in LDS once per block.
// Lane l handles h[t][k*256 + 4l .. +3] float4 chunks, k=0..7, accumulating
// 8 expert dots; shuffle-reduce across the 64-lane wave; lane 0 picks top-2,
// applies sigmoid, writes the dense [E,T] score column (zeros elsewhere)
// to both router_scores (out0) and router_probs (out2, same flat layout).
// ---------------------------------------------------------------------------
__global__ __launch_bounds__(256) void router_scores_kernel(
    const float* __restrict__ h, const float* __restrict__ w,
    float* __restrict__ out0, float* __restrict__ out2)
{
    __shared__ float wlds[N_EXPERTS * HIDDEN];  // 64 KB
    const float4* w4  = (const float4*)w;
    float4*       wl4 = (float4*)wlds;
    for (int i = threadIdx.x; i < (N_EXPERTS * HIDDEN) / 4; i += 256)
        wl4[i] = w4[i];
    __syncthreads();

    const int wave = threadIdx.x >> 6;
    const int lane = threadIdx.x & 63;
    const int t = blockIdx.x * 4 + wave;  // grid = 1024 blocks -> t in [0,4096)

    const float4* h4 = (const float4*)(h + (size_t)t * HIDDEN);
    float acc[N_EXPERTS];
    #pragma unroll
    for (int e = 0; e < N_EXPERTS; e++) acc[e] = 0.f;

    #pragma unroll
    for (int k = 0; k < 8; k++) {
        float4 hv = h4[k * 64 + lane];
        #pragma unroll
        for (int e = 0; e < N_EXPERTS; e++) {
            float4 wv = wl4[e * 512 + k * 64 + lane];
            acc[e] += hv.x * wv.x + hv.y * wv.y + hv.z * wv.z + hv.w * wv.w;
        }
    }

    // 64-lane shuffle reduction for each expert accumulator
    #pragma unroll
    for (int e = 0; e < N_EXPERTS; e++) {
        #pragma unroll
        for (int off = 32; off > 0; off >>= 1)
            acc[e] += __shfl_down(acc[e], off, 64);
    }

    if (lane == 0) {
        // top-2 of 8 (strict >, first-index-wins matches lax.top_k; order of
        // the two winners is irrelevant for the scattered output)
        int i1 = 0; float v1 = acc[0];
        #pragma unroll
        for (int e = 1; e < N_EXPERTS; e++)
            if (acc[e] > v1) { v1 = acc[e]; i1 = e; }
        int i2 = -1; float v2 = -INFINITY;
        #pragma unroll
        for (int e = 0; e < N_EXPERTS; e++)
            if (e != i1 && acc[e] > v2) { v2 = acc[e]; i2 = e; }

        float s1 = 1.f / (1.f + expf(-v1));
        float s2 = 1.f / (1.f + expf(-v2));

        #pragma unroll
        for (int e = 0; e < N_EXPERTS; e++) {
            float val = (e == i1) ? s1 : ((e == i2) ? s2 : 0.f);
            out0[e * T_TOKENS + t] = val;
            out2[e * T_TOKENS + t] = val;
        }
    }
}

extern "C" void kernel_launch(void* const* d_in, const int* in_sizes, int n_in,
                              void* d_out, int out_size, void* d_ws, size_t ws_size,
                              hipStream_t stream) {
    const float* h = (const float*)d_in[0];   // [4096, 2048] f32
    const float* w = (const float*)d_in[1];   // [8, 2048] f32
    // d_in[2] = top_k (always 2 for this problem)

    float* out  = (float*)d_out;
    float* out0 = out;                                   // router_scores [8,4096]
    float* out1 = out + N_EXPERTS * T_TOKENS;            // router_indices [32768,2048]
    float* out2 = out1 + (size_t)N_EXPERTS * T_TOKENS * HIDDEN;  // router_probs [32768,1]

    hipLaunchKernelGGL(fill_indices_kernel, dim3(8192), dim3(256), 0, stream, out1);
    hipLaunchKernelGGL(router_scores_kernel, dim3(1024), dim3(256), 0, stream,
                       h, w, out0, out2);
}